// Round 1
// baseline (466.249 us; speedup 1.0000x reference)
//
#include <hip/hip_runtime.h>

// TopK (K=64) per row, B=4096 x D=16384 fp32.
// out = zeros; out[row, idx_of_top64] = value.
//
// Strategy: 1 block per row. 512 threads x 32 elements each, kept in
// registers as order-preserving uints. Exact 64th-largest found by 4-pass
// radix-256 select (LDS histogram + wave-0 suffix scan). Single coalesced
// float4 write pass covers the whole output row (no memset needed).
// Ties at the threshold resolved lowest-index-first (lax.top_k semantics).

#define TK_D      16384
#define TK_K      64
#define TK_BLOCK  512
#define TK_NF4    8            // float4s per thread  (TK_D / TK_BLOCK / 4)
#define TK_VPT    32           // values per thread
#define TK_EQCAP  1024         // cap on boundary-tie list (random data: ~1)

__launch_bounds__(TK_BLOCK, 4)
__global__ void topk_scatter_kernel(const float* __restrict__ x,
                                    float* __restrict__ out) {
    __shared__ int      sh_hist[256];
    __shared__ unsigned sh_prefix;
    __shared__ int      sh_rem;
    __shared__ unsigned sh_counts;          // c_gt | (c_eq << 16)
    __shared__ int      sh_eqn;
    __shared__ int      sh_eqidx[TK_EQCAP];

    const int row = blockIdx.x;
    const int tid = threadIdx.x;
    const float4* __restrict__ xrow = (const float4*)(x + (size_t)row * TK_D);
    float4* __restrict__ orow       = (float4*)(out + (size_t)row * TK_D);

    // ---- load 32 elements (8 coalesced float4s), map to ordered uints ----
    // ordered: u = b ^ (b<0 ? 0xFFFFFFFF : 0x80000000); larger u <=> larger f
    unsigned u[TK_VPT];
    #pragma unroll
    for (int k = 0; k < TK_NF4; k++) {
        float4 v = xrow[tid + k * TK_BLOCK];
        unsigned b0 = __float_as_uint(v.x);
        unsigned b1 = __float_as_uint(v.y);
        unsigned b2 = __float_as_uint(v.z);
        unsigned b3 = __float_as_uint(v.w);
        u[4*k+0] = b0 ^ ((unsigned)((int)b0 >> 31) | 0x80000000u);
        u[4*k+1] = b1 ^ ((unsigned)((int)b1 >> 31) | 0x80000000u);
        u[4*k+2] = b2 ^ ((unsigned)((int)b2 >> 31) | 0x80000000u);
        u[4*k+3] = b3 ^ ((unsigned)((int)b3 >> 31) | 0x80000000u);
    }

    if (tid == 0) { sh_prefix = 0u; sh_rem = TK_K; sh_counts = 0u; sh_eqn = 0; }

    // ---- 4-pass radix-256 select: find bit pattern of K-th largest ----
    #pragma unroll
    for (int p = 0; p < 4; p++) {
        if (tid < 256) sh_hist[tid] = 0;
        __syncthreads();
        const unsigned pref = sh_prefix;
        const int      rem  = sh_rem;
        const int      shift = 24 - 8 * p;
        #pragma unroll
        for (int i = 0; i < TK_VPT; i++) {
            bool in_scope = (p == 0) || ((u[i] >> (shift + 8)) == pref);
            if (in_scope) atomicAdd(&sh_hist[(u[i] >> shift) & 0xFF], 1);
        }
        __syncthreads();
        // wave 0: suffix-sum over 256 bins, pick digit d:  S(d)>=rem>S(d+1)
        if (tid < 64) {
            const int lane = tid;
            int h0 = sh_hist[4*lane+0], h1 = sh_hist[4*lane+1];
            int h2 = sh_hist[4*lane+2], h3 = sh_hist[4*lane+3];
            int local = h0 + h1 + h2 + h3;
            int suf = local;                 // becomes sum over lanes >= lane
            #pragma unroll
            for (int off = 1; off < 64; off <<= 1) {
                int o = __shfl_down(suf, off);
                if (lane + off < 64) suf += o;
            }
            int A  = suf - local;            // sum over lanes > lane
            int S3 = A + h3, S2 = S3 + h2, S1 = S2 + h1, S0 = S1 + h0;
            int d = -1, ab = 0;
            if      (S3 >= rem && A  < rem) { d = 4*lane+3; ab = A;  }
            else if (S2 >= rem && S3 < rem) { d = 4*lane+2; ab = S3; }
            else if (S1 >= rem && S2 < rem) { d = 4*lane+1; ab = S2; }
            else if (S0 >= rem && S1 < rem) { d = 4*lane+0; ab = S1; }
            if (d >= 0) {                    // exactly one lane hits this
                sh_prefix = (pref << 8) | (unsigned)d;
                sh_rem    = rem - ab;
            }
        }
        __syncthreads();
    }
    const unsigned T = sh_prefix;            // ordered-uint of 64th largest

    // ---- count strictly-greater and equal (exact tie accounting) ----
    {
        int cgt = 0, ceq = 0;
        #pragma unroll
        for (int i = 0; i < TK_VPT; i++) { cgt += (u[i] > T); ceq += (u[i] == T); }
        unsigned packed = (unsigned)cgt | ((unsigned)ceq << 16);
        #pragma unroll
        for (int off = 32; off > 0; off >>= 1)
            packed += __shfl_down(packed, off);
        if ((tid & 63) == 0) atomicAdd(&sh_counts, packed);
    }

    // inverse map for output value at threshold
    const float Tf = __uint_as_float(T ^ ((unsigned)((int)(~T) >> 31) | 0x80000000u));

    // ---- write pass: val > T ? val : 0 ; record boundary ties ----
    #pragma unroll
    for (int k = 0; k < TK_NF4; k++) {
        float4 o;
        const int base = 4 * (tid + k * TK_BLOCK);
        #pragma unroll
        for (int c = 0; c < 4; c++) {
            unsigned uu = u[4*k+c];
            float f = __uint_as_float(uu ^ ((unsigned)((int)(~uu) >> 31) | 0x80000000u));
            ((float*)&o)[c] = (uu > T) ? f : 0.0f;
            if (uu == T) {
                int pos = atomicAdd(&sh_eqn, 1);
                if (pos < TK_EQCAP) sh_eqidx[pos] = base + c;
            }
        }
        orow[tid + k * TK_BLOCK] = o;
    }
    __syncthreads();

    // ---- scatter accepted ties: lowest column indices first ----
    const unsigned cnts = sh_counts;
    const int c_gt = (int)(cnts & 0xFFFFu);
    const int need = TK_K - c_gt;            // >= 1 by construction
    const int L = min(sh_eqn, TK_EQCAP);
    for (int i = tid; i < L; i += TK_BLOCK) {
        int col  = sh_eqidx[i];
        int rank = 0;
        for (int j = 0; j < L; j++) rank += (sh_eqidx[j] < col);
        if (rank < need) out[(size_t)row * TK_D + col] = Tf;
    }
}

extern "C" void kernel_launch(void* const* d_in, const int* in_sizes, int n_in,
                              void* d_out, int out_size, void* d_ws, size_t ws_size,
                              hipStream_t stream) {
    const float* x = (const float*)d_in[0];
    float* out = (float*)d_out;
    const int B = in_sizes[0] / TK_D;        // 4096
    topk_scatter_kernel<<<B, TK_BLOCK, 0, stream>>>(x, out);
}

// Round 2
// 444.631 us; speedup vs baseline: 1.0486x; 1.0486x over previous
//
#include <hip/hip_runtime.h>

// TopK (K=64) per row, B=4096 x D=16384 fp32.
// out = zeros; out[row, top64 idx] = value.
//
// R2: row staged in LDS via global_load_lds DMA (width 16). Raw float bits in
// LDS; order-preserving uint computed on the fly. Exact 64th-largest via
// 3-pass radix select (11+11+10 bits, 2048 bins) -- spreads histogram atomics
// vs 256 bins, and radix invariant gives need = rem after last pass (no
// separate count phase). All 8 waves cooperate in the bin suffix-scan.
// Ties at threshold resolved lowest-index-first (lax.top_k semantics).

#define TK_D      16384
#define TK_K      64
#define TK_BLOCK  512
#define TK_NF4    8            // float4 chunks per thread (TK_D/4/TK_BLOCK)
#define TK_BINS   2048
#define TK_EQCAP  1024         // boundary-tie list cap (random data: ~1)

__device__ __forceinline__ unsigned ord_map(unsigned b) {
    // larger u <=> larger float (handles negatives)
    return b ^ ((unsigned)((int)b >> 31) | 0x80000000u);
}

__launch_bounds__(TK_BLOCK, 4)
__global__ void topk_scatter_kernel(const float* __restrict__ x,
                                    float* __restrict__ out) {
    __shared__ __align__(16) unsigned sh_vals[TK_D];   // raw float bits, 64 KiB
    __shared__ int      sh_hist[TK_BINS];              // 8 KiB
    __shared__ int      sh_wsum[8];
    __shared__ unsigned sh_prefix;
    __shared__ int      sh_rem;
    __shared__ int      sh_eqn;
    __shared__ int      sh_eqidx[TK_EQCAP];

    const int row  = blockIdx.x;
    const int tid  = threadIdx.x;
    const int lane = tid & 63;
    const int wv   = tid >> 6;

    const float4* __restrict__ xrow = (const float4*)(x + (size_t)row * TK_D);

    // ---- async DMA global -> LDS: 16 B/lane, wave-uniform LDS base ----
    #pragma unroll
    for (int i = 0; i < TK_NF4; i++) {
        const int c4 = wv * 64 + i * TK_BLOCK;         // wave-uniform float4 idx
        __builtin_amdgcn_global_load_lds(
            (const __attribute__((address_space(1))) void*)(xrow + c4 + lane),
            (__attribute__((address_space(3))) void*)(&sh_vals[4 * c4]),
            16, 0, 0);
    }

    ((int4*)sh_hist)[tid] = int4{0, 0, 0, 0};          // zero 4 bins/thread
    if (tid == 0) { sh_prefix = 0u; sh_rem = TK_K; sh_eqn = 0; }
    __syncthreads();                                   // drains DMA (vmcnt 0)

    // ---- 3-pass radix select over ordered-uint bits ----
    // pass p: histogram bits [histshift .. histshift+nbits), scope = upper bits
    const int histshift[3]  = {21, 10, 0};
    const int scopeshift[3] = {0, 21, 10};
    const int nbits[3]      = {11, 11, 10};

    for (int p = 0; p < 3; p++) {
        const unsigned pref = sh_prefix;
        const int      rem  = sh_rem;
        const int      hs   = histshift[p];
        const unsigned msk  = (1u << nbits[p]) - 1u;
        #pragma unroll
        for (int i = 0; i < TK_NF4; i++) {
            uint4 b = ((const uint4*)sh_vals)[tid + i * TK_BLOCK];
            #pragma unroll
            for (int c = 0; c < 4; c++) {
                unsigned u = ord_map(((const unsigned*)&b)[c]);
                bool in_scope = (p == 0) || ((u >> scopeshift[p] >> nbits[0]) == pref);
                // note: scope compare is (u >> (hs+nbits[p])) == pref; for
                // p=1: u>>21(+... ) -- computed below explicitly instead:
                in_scope = (p == 0) || ((u >> (hs + nbits[p])) == pref);
                if (in_scope) atomicAdd(&sh_hist[(u >> hs) & msk], 1);
            }
        }
        __syncthreads();

        // hierarchical suffix scan: thread t owns bins 4t..4t+3 (ascending)
        int h0 = sh_hist[4 * tid + 0], h1 = sh_hist[4 * tid + 1];
        int h2 = sh_hist[4 * tid + 2], h3 = sh_hist[4 * tid + 3];
        int local = h0 + h1 + h2 + h3;
        int suf = local;                               // sum over lanes >= lane
        #pragma unroll
        for (int off = 1; off < 64; off <<= 1) {
            int o = __shfl_down(suf, off);
            if (lane + off < 64) suf += o;
        }
        if (lane == 0) sh_wsum[wv] = suf;              // wave total
        __syncthreads();

        ((int4*)sh_hist)[tid] = int4{0, 0, 0, 0};      // re-zero for next pass

        int above = 0;                                 // bins above this wave
        #pragma unroll
        for (int w2 = 0; w2 < 8; w2++)
            if (w2 > wv) above += sh_wsum[w2];

        int a3 = above + (suf - local);                // suffix strictly above bin 4t+3
        int S3 = a3 + h3, S2 = S3 + h2, S1 = S2 + h1, S0 = S1 + h0;
        int d = -1, ab = 0;
        if      (S3 >= rem && a3 < rem) { d = 4 * tid + 3; ab = a3; }
        else if (S2 >= rem && S3 < rem) { d = 4 * tid + 2; ab = S3; }
        else if (S1 >= rem && S2 < rem) { d = 4 * tid + 1; ab = S2; }
        else if (S0 >= rem && S1 < rem) { d = 4 * tid + 0; ab = S1; }
        if (d >= 0) {                                  // exactly one thread
            sh_prefix = (pref << nbits[p]) | (unsigned)d;
            sh_rem    = rem - ab;
        }
        __syncthreads();
    }

    const unsigned T    = sh_prefix;                   // ordered uint of K-th largest
    const int      need = sh_rem;                      // K - count(u > T), >= 1

    // ---- write pass: val > T ? val : 0 ; record boundary ties ----
    float4* __restrict__ orow = (float4*)(out + (size_t)row * TK_D);
    #pragma unroll
    for (int i = 0; i < TK_NF4; i++) {
        const int c4 = tid + i * TK_BLOCK;
        uint4 b = ((const uint4*)sh_vals)[c4];
        float4 o;
        #pragma unroll
        for (int c = 0; c < 4; c++) {
            unsigned raw = ((const unsigned*)&b)[c];
            unsigned u   = ord_map(raw);
            ((float*)&o)[c] = (u > T) ? __uint_as_float(raw) : 0.0f;
            if (u == T) {
                int pos = atomicAdd(&sh_eqn, 1);
                if (pos < TK_EQCAP) sh_eqidx[pos] = 4 * c4 + c;
            }
        }
        orow[c4] = o;
    }
    __syncthreads();

    // ---- scatter accepted ties: lowest column indices first ----
    const int L = min(sh_eqn, TK_EQCAP);
    for (int i = tid; i < L; i += TK_BLOCK) {
        int col  = sh_eqidx[i];
        int rank = 0;
        for (int j = 0; j < L; j++) rank += (sh_eqidx[j] < col);
        if (rank < need)
            out[(size_t)row * TK_D + col] = __uint_as_float(sh_vals[col]);
    }
}

extern "C" void kernel_launch(void* const* d_in, const int* in_sizes, int n_in,
                              void* d_out, int out_size, void* d_ws, size_t ws_size,
                              hipStream_t stream) {
    const float* x = (const float*)d_in[0];
    float* out = (float*)d_out;
    const int B = in_sizes[0] / TK_D;                  // 4096
    topk_scatter_kernel<<<B, TK_BLOCK, 0, stream>>>(x, out);
}